// Round 5
// baseline (8974.597 us; speedup 1.0000x reference)
//
#include <hip/hip_runtime.h>
#include <cstdint>

// Problem constants
static constexpr int BATCH  = 32;
static constexpr int TLEN   = 2048;
static constexpr int DIN    = 256;    // input dim
static constexpr int HDIM   = 512;    // hidden dim
static constexpr int G4     = 2048;   // 4*HDIM (gate cols, order i,f,g,o)
static constexpr int NSLICE = 8;      // blocks per batch
static constexpr int HCB    = 64;     // h-cols per block/slice
static constexpr int CPB    = 256;    // gate-cols per block (4 * HCB)
static constexpr int NTHR   = 512;    // 8 waves
static constexpr int NWAVE  = 8;
static constexpr int XKW    = 32;     // x k-range per wave  [32w, 32w+32)
static constexpr int HKW    = 64;     // h k-range per wave  [64w, 64w+64) == slice w
static constexpr int NBLK   = BATCH * NSLICE;  // 256 blocks = 1/CU

typedef _Float16 h2v __attribute__((ext_vector_type(2)));
typedef unsigned long long u64;
typedef uint32_t u32;

__device__ __forceinline__ u32 pack_f16x2(float a, float b) {
    // RTZ pack is fine at these magnitudes; single instr.
    return __builtin_bit_cast(u32, __builtin_amdgcn_cvt_pkrtz(a, b));
}

__device__ __forceinline__ float dot2f(u32 w, u32 u, float acc) {
#if __has_builtin(__builtin_amdgcn_fdot2)
    return __builtin_amdgcn_fdot2(__builtin_bit_cast(h2v, w),
                                  __builtin_bit_cast(h2v, u), acc, false);
#else
    h2v a = __builtin_bit_cast(h2v, w);
    h2v b = __builtin_bit_cast(h2v, u);
    return acc + (float)a[0] * (float)b[0] + (float)a[1] * (float)b[1];
#endif
}

__device__ __forceinline__ float sigmoidf_(float x) {
    return 1.0f / (1.0f + __expf(-x));
}
__device__ __forceinline__ float tanhf_(float x) {
    return 1.0f - 2.0f / (1.0f + __expf(2.0f * x));
}

// x-weight LDS layout: ONE index function for write and read (R4 bug: the
// read path re-derived this index and dropped a *4 -> wrong weights).
// Lane l reads a uint4 at [w][q][m4][l] -> 1024B contiguous per wave access,
// conflict-free.
__device__ __forceinline__ int xw_idx(int w, int q, int m4, int l, int j) {
    return (((w * 4 + q) * 4 + m4) * 64 + l) * 4 + j;
}

// Persistent LSTM, one launch = all 2048 steps.
// grid = 32 batches x 8 slices, block = 512 threads (8 waves), 1 block/CU.
//
// Cross-block h exchange: TAGGED u64 words, relaxed agent atomics.
//   word i of slice s at step t+1: (u64(t+1) << 32) | f16x2(h[64s+2i], h[64s+2i+1])
// Reader polls the data word itself for tag == t -> no producer vmcnt drain,
// no flag store, no separate flag->data round trip. 2-deep parity buffer
// (t&1); exact-tag poll is race-free: publishing tag t+2 requires the
// producer block to have passed __syncthreads at t+1, which requires all its
// waves' tag-(t+1) polls, which requires every slice's wave-0 publish of
// t+1, which requires every wave of every slice to have passed its tag-t
// poll. memset(0) == tag 0, h=0 == initial state.
//
// Wave w's h chunk [64w,64w+64) == slice w's output -> each wave polls only
// its own 32 words, straight into registers (no LDS hop, no stage barrier).
// x is loaded broadcast from global BEFORE the poll (latency hidden) and
// packed in-register with v_cvt_pkrtz. One __syncthreads per step (gate
// partials, parity-double-buffered in LDS).
__global__ __launch_bounds__(NTHR, 2) void lstm_persist(
    const float* __restrict__ x, const int* __restrict__ lens,
    const float* __restrict__ Wi, const float* __restrict__ Wh,
    const float* __restrict__ bias, float* __restrict__ out,
    u64* __restrict__ hbuf)
{
    // Block -> (batch, slice); all 8 slices of a batch land on one XCD under
    // the blockIdx%8 heuristic (perf only, not correctness).
    const int bid = blockIdx.x;
    const int xcd = bid & 7;
    const int t8  = bid >> 3;          // 0..31
    const int b   = xcd * 4 + (t8 & 3);
    const int s   = t8 >> 2;           // slice 0..7

    const int tid = threadIdx.x;
    const int w   = tid >> 6;          // wave 0..7
    const int l   = tid & 63;          // lane -> gate-cols {4l..4l+3}

    // x-part weights in LDS (128 KB) so the hot h-part weights stay
    // register-resident within the 256-reg/wave budget.
    __shared__ __align__(16) u32 xw_lds[NWAVE * 4 * 4 * 64 * 4]; // 128 KB
    __shared__ float gp[2][NWAVE][CPB];                          // 16 KB

    // ---- one-time: weight slices ----------------------------------------
    // gate-col mapping: local col c = 4l+q -> gcol = (c>>6)*HDIM + s*64 + (c&63)
    u32 wh_r[4][HKW / 2];   // h-part: 32 u32 per col, registers
    #pragma unroll
    for (int q = 0; q < 4; ++q) {
        const int c    = 4 * l + q;
        const int gcol = (c >> 6) * HDIM + s * HCB + (c & 63);
        #pragma unroll
        for (int m = 0; m < HKW / 2; ++m) {
            const int k0 = HKW * w + 2 * m;
            wh_r[q][m] = pack_f16x2(Wh[(size_t)k0 * G4 + gcol],
                                    Wh[(size_t)(k0 + 1) * G4 + gcol]);
        }
        #pragma unroll
        for (int m = 0; m < XKW / 2; ++m) {   // x-part -> LDS
            const int k0 = XKW * w + 2 * m;
            const u32 pw = pack_f16x2(Wi[(size_t)k0 * G4 + gcol],
                                      Wi[(size_t)(k0 + 1) * G4 + gcol]);
            xw_lds[xw_idx(w, q, m >> 2, l, m & 3)] = pw;
        }
    }

    // wave-0 persistent state (lane j owns h-col s*64+j)
    float c_st = 0.f, lc_st = 0.f, lh_st = 0.f;
    float b_i = 0.f, b_f = 0.f, b_g = 0.f, b_o = 0.f;
    if (tid < HCB) {
        const int col = s * HCB + tid;
        b_i = bias[col];
        b_f = bias[HDIM + col];
        b_g = bias[2 * HDIM + col];
        b_o = bias[3 * HDIM + col];
    }
    const int len_b = lens[b];

    const float* xb = x + (size_t)b * TLEN * DIN;
    float* ys = out + 2 * BATCH * HDIM;   // out = [lc | lh | ys]

    for (int t = 0; t < TLEN; ++t) {
        const int p = t & 1;

        // ---- x chunk: broadcast loads issued before the poll ------------
        float4 xq[8];
        const float4* xv = (const float4*)(xb + (size_t)t * DIN + XKW * w);
        #pragma unroll
        for (int i = 0; i < 8; ++i) xq[i] = xv[i];

        // ---- poll own h chunk (tagged words, exact tag == t) ------------
        const u64* hw = hbuf + ((size_t)p * BATCH + b) * (HDIM / 2) + (HKW / 2) * w;
        u32 lo[HKW / 2];
        {
            const u32 tagv = (u32)t;
            for (;;) {
                u64 v[HKW / 2];
                #pragma unroll
                for (int m = 0; m < HKW / 2; ++m)
                    v[m] = __hip_atomic_load(&hw[m], __ATOMIC_RELAXED,
                                             __HIP_MEMORY_SCOPE_AGENT);
                u32 bad = 0;
                #pragma unroll
                for (int m = 0; m < HKW / 2; ++m)
                    bad |= ((u32)(v[m] >> 32)) ^ tagv;
                if (bad == 0) {   // uniform across lanes (same addresses)
                    #pragma unroll
                    for (int m = 0; m < HKW / 2; ++m) lo[m] = (u32)v[m];
                    break;
                }
            }
        }

        // ---- dot phase --------------------------------------------------
        float a0 = 0.f, a1 = 0.f, a2 = 0.f, a3 = 0.f;
        // x part: pack f32->f16x2 in-register, weights from LDS
        u32 px[XKW / 2];
        #pragma unroll
        for (int i = 0; i < 8; ++i) {
            px[2 * i]     = pack_f16x2(xq[i].x, xq[i].y);
            px[2 * i + 1] = pack_f16x2(xq[i].z, xq[i].w);
        }
        #pragma unroll
        for (int q = 0; q < 4; ++q) {
            float aq = 0.f;
            #pragma unroll
            for (int m4 = 0; m4 < 4; ++m4) {
                const uint4 ww4 = *(const uint4*)&xw_lds[xw_idx(w, q, m4, l, 0)];
                aq = dot2f(ww4.x, px[4 * m4 + 0], aq);
                aq = dot2f(ww4.y, px[4 * m4 + 1], aq);
                aq = dot2f(ww4.z, px[4 * m4 + 2], aq);
                aq = dot2f(ww4.w, px[4 * m4 + 3], aq);
            }
            if (q == 0) a0 = aq; else if (q == 1) a1 = aq;
            else if (q == 2) a2 = aq; else a3 = aq;
        }
        // h part: register weights x polled words
        #pragma unroll
        for (int m = 0; m < HKW / 2; ++m) {
            a0 = dot2f(wh_r[0][m], lo[m], a0);
            a1 = dot2f(wh_r[1][m], lo[m], a1);
            a2 = dot2f(wh_r[2][m], lo[m], a2);
            a3 = dot2f(wh_r[3][m], lo[m], a3);
        }
        float4 av; av.x = a0; av.y = a1; av.z = a2; av.w = a3;
        *(float4*)&gp[p][w][4 * l] = av;
        __syncthreads();   // the only per-step barrier

        // ---- update phase: wave 0 reduces + activations + publish -------
        if (tid < HCB) {
            float si = b_i, sf = b_f, sg = b_g, so = b_o;
            #pragma unroll
            for (int ww = 0; ww < NWAVE; ++ww) {
                si += gp[p][ww][tid];
                sf += gp[p][ww][HCB + tid];
                sg += gp[p][ww][2 * HCB + tid];
                so += gp[p][ww][3 * HCB + tid];
            }
            const float ig = sigmoidf_(si);
            const float fg = sigmoidf_(sf);
            const float gg = tanhf_(sg);
            const float og = sigmoidf_(so);
            const float cn = fg * c_st + ig * gg;
            const float hn = og * tanhf_(cn);
            c_st = cn;
            if (t < len_b) { lc_st = cn; lh_st = hn; }
            // publish tagged h_{t+1}: lanes 0..31 store one u64 each
            const float ha = __shfl(hn, (2 * tid) & 63);
            const float hb = __shfl(hn, (2 * tid + 1) & 63);
            if (tid < HCB / 2) {
                const u64 word = ((u64)(u32)(t + 1) << 32) | (u64)pack_f16x2(ha, hb);
                u64* dst = hbuf + ((size_t)((t + 1) & 1) * BATCH + b) * (HDIM / 2)
                         + (HKW / 2) * s + tid;
                __hip_atomic_store(dst, word, __ATOMIC_RELAXED,
                                   __HIP_MEMORY_SCOPE_AGENT);
            }
            // ys output (fp32, unmasked like the reference scan)
            ys[((size_t)b * TLEN + t) * HDIM + s * HCB + tid] = hn;
        }
        // no second barrier: gp is parity-double-buffered, next iteration
        // writes gp[p^1] while wave 0 may still be reading gp[p].
    }

    // latched carry outputs
    if (tid < HCB) {
        out[(size_t)b * HDIM + s * HCB + tid] = lc_st;
        out[BATCH * HDIM + (size_t)b * HDIM + s * HCB + tid] = lh_st;
    }
}

extern "C" void kernel_launch(void* const* d_in, const int* in_sizes, int n_in,
                              void* d_out, int out_size, void* d_ws, size_t ws_size,
                              hipStream_t stream)
{
    const float* x    = (const float*)d_in[0];   // [32,2048,256] f32
    const int*   lens = (const int*)d_in[1];     // [32] i32
    const float* Wi   = (const float*)d_in[2];   // [256,2048] f32
    const float* Wh   = (const float*)d_in[3];   // [512,2048] f32
    const float* bias = (const float*)d_in[4];   // [2048] f32
    float* out = (float*)d_out;                  // [lc(16384) | lh(16384) | ys]

    u64* hbuf = (u64*)d_ws;                      // [2][32][256] tagged u64
    const size_t init_bytes = (size_t)2 * BATCH * (HDIM / 2) * sizeof(u64); // 128 KB
    // tag 0 + h=0 == initial state; d_ws is re-poisoned before every launch.
    (void)hipMemsetAsync(d_ws, 0, init_bytes, stream);

    hipLaunchKernelGGL(lstm_persist, dim3(NBLK), dim3(NTHR), 0, stream,
                       x, lens, Wi, Wh, bias, out, hbuf);
}